// Round 8
// baseline (18.988 us; speedup 1.0000x reference)
//
#include <hip/hip_runtime.h>
#include <hip/hip_fp16.h>

// scores[r,t] = b2 + sum_h W2[h] * relu(rp[r,h] + tp[t,h])
//   rp = robot @ W1[:256] + b1 ; tp = task @ W1[256:]
// K1 gemm_packed (256 blk x 256 thr): MFMA f16, A=W1^T (M=h) staged in LDS,
//    B=robot/task built per-ks directly from global (16B/lane contiguous).
//    Writes ws as packed half2 h-pairs rpP/tpP [256 hp][512 r], bias folded.
// K2 score (256 blk x 512 thr): pure-copy staging, v_pk_add/max_f16 +
//    v_dot2_f32_f16, 8 waves split 256 h-pairs, in-LDS reduce.
// ws: rpP uint[256*512] | tpP uint[256*512]  (1 MB)
// NOTE: cooperative launch / grid.sync deadlocked the container (R6) — banned.

#define RT 512
#define DD 256
#define HD 512

typedef _Float16 h2 __attribute__((ext_vector_type(2)));
typedef _Float16 h8 __attribute__((ext_vector_type(8)));
typedef float f32x4 __attribute__((ext_vector_type(4)));

__device__ inline unsigned h2u(h2 v) { return __builtin_bit_cast(unsigned, v); }
__device__ inline h2 u2h(unsigned u) { return __builtin_bit_cast(h2, u); }
__device__ inline h2 pk(float a, float b) {
    return __builtin_bit_cast(h2, __builtin_amdgcn_cvt_pkrtz(a, b));  // v_cvt_pkrtz_f16_f32
}

// ---------------- K1: GEMM -> packed half2 ws ----------------
// Block b: z=b>>7, rtile=(b&15)*32, htile=((b>>4)&7)*64. 4 waves:
// wave>>1 = r-strip (16 rows), wave&1 = h-strip (32 of 64 h).
__global__ __launch_bounds__(256) void gemm_packed(
    const float* __restrict__ robot, const float* __restrict__ task,
    const float* __restrict__ W1, const float* __restrict__ b1,
    unsigned* __restrict__ wsu)
{
    __shared__ __attribute__((aligned(16))) unsigned smem[8192];   // 32 KB
    unsigned short* Ws = (unsigned short*)smem;    // f16 [64 h][256 k], swz

    const int tid = threadIdx.x;
    const int wave = tid >> 6, lane = tid & 63;
    const int b = blockIdx.x;
    const int z = b >> 7, sub = b & 127;
    const int rtile = (sub & 15) * 32;
    const int htile = (sub >> 4) * 64;
    const float* X = z ? task : robot;
    const float* Wz = W1 + z * DD * HD;

    // stage Ws: W1[k][h] -> Ws[h][k] (lane-coalesced in h), f32->f16
    {
        const int hh = tid & 63, k0 = (tid >> 6) * 64;
        #pragma unroll
        for (int j = 0; j < 8; ++j) {
            float f[8];
            #pragma unroll
            for (int u = 0; u < 8; ++u)
                f[u] = Wz[(k0 + 8 * j + u) * HD + htile + hh];
            uint4 o = make_uint4(h2u(pk(f[0], f[1])), h2u(pk(f[2], f[3])),
                                 h2u(pk(f[4], f[5])), h2u(pk(f[6], f[7])));
            *(uint4*)((char*)Ws + ((hh * 512 + k0 * 2 + j * 16) ^ ((hh & 7) << 4))) = o;
        }
    }
    __syncthreads();

    const int wstrip = wave >> 1;          // r-strip
    const int wh = (wave & 1) * 32;        // h-strip base
    const int lm = lane & 15;
    const int lkb = (lane >> 4) * 16;      // k-slice byte offset
    const int xrow = rtile + wstrip * 16 + lm;
    const float* Xp = &X[xrow * DD];

    f32x4 acc0 = {0.f, 0.f, 0.f, 0.f}, acc1 = {0.f, 0.f, 0.f, 0.f};
    #pragma unroll
    for (int ks = 0; ks < 8; ++ks) {
        // B-frag: X[xrow][ks*32 + (lane>>4)*8 .. +8) from global, f32->f16
        const float* xp = Xp + ks * 32 + (lane >> 4) * 8;
        float4 v0 = *(const float4*)xp, v1 = *(const float4*)(xp + 4);
        uint4 bu = make_uint4(h2u(pk(v0.x, v0.y)), h2u(pk(v0.z, v0.w)),
                              h2u(pk(v1.x, v1.y)), h2u(pk(v1.z, v1.w)));
        h8 bb = __builtin_bit_cast(h8, bu);
        const int h0 = wh + lm, h1 = wh + 16 + lm;
        h8 a0 = *(const h8*)((const char*)Ws + ((h0 * 512 + ks * 64 + lkb) ^ ((h0 & 7) << 4)));
        h8 a1 = *(const h8*)((const char*)Ws + ((h1 * 512 + ks * 64 + lkb) ^ ((h1 & 7) << 4)));
        acc0 = __builtin_amdgcn_mfma_f32_16x16x32_f16(a0, bb, acc0, 0, 0, 0);
        acc1 = __builtin_amdgcn_mfma_f32_16x16x32_f16(a1, bb, acc1, 0, 0, 0);
    }

    // epilogue: D col(lane&15)=r, rows (lane>>4)*4+j = h; pack h-pairs
    unsigned* P = wsu + z * (256 * RT);
    const int r = xrow;
    #pragma unroll
    for (int mf = 0; mf < 2; ++mf) {
        f32x4 acc = mf ? acc1 : acc0;
        const int hq = htile + wh + mf * 16 + (lane >> 4) * 4;
        float4 bv = make_float4(0.f, 0.f, 0.f, 0.f);
        if (z == 0) bv = *(const float4*)&b1[hq];
        P[((hq >> 1) + 0) * RT + r] = h2u(pk(acc[0] + bv.x, acc[1] + bv.y));
        P[((hq >> 1) + 1) * RT + r] = h2u(pk(acc[2] + bv.z, acc[3] + bv.w));
    }
}

// ---------------- K2: score ----------------
// grid (16,16), 512 thr (8 waves), 32x32 out tile, waves split 256 h-pairs.
__global__ __launch_bounds__(512) void score(
    const unsigned* __restrict__ wsu, const float* __restrict__ W2,
    const float* __restrict__ b2, float* __restrict__ out)
{
    __shared__ __attribute__((aligned(16))) unsigned smem[16384];  // 64 KB
    unsigned* rs = smem;            // [256 hp][32 r]
    unsigned* ts = smem + 8192;     // [256 hp][32 t]

    const unsigned* rpP = wsu;
    const unsigned* tpP = wsu + 256 * RT;
    const int tid = threadIdx.x;
    const int rbase = blockIdx.y * 32, tbase = blockIdx.x * 32;

    #pragma unroll
    for (int i = 0; i < 8; ++i) {
        int u = tid + 512 * i;              // 0..4095 uint4-units
        int hp = (u >> 3) & 255, rq = (u & 7) * 4;
        if (u < 2048)
            *(uint4*)&rs[hp * 32 + rq] = *(const uint4*)&rpP[hp * RT + rbase + rq];
        else
            *(uint4*)&ts[hp * 32 + rq] = *(const uint4*)&tpP[hp * RT + tbase + rq];
    }
    __syncthreads();

    const int wave = tid >> 6, lane = tid & 63;
    const int ly = (lane >> 3) & 7, lx = lane & 7;   // 8x8 lanes, 4x4 micro
    const h2 hzero = {};
    float acc[4][4] = {};
    const int s0 = wave * 32;
    #pragma unroll 4
    for (int s = s0; s < s0 + 32; ++s) {
        uint4 da = *(const uint4*)&rs[s * 32 + 4 * ly];   // broadcast, conflict-free
        uint4 dc = *(const uint4*)&ts[s * 32 + 4 * lx];
        float2 wf = *(const float2*)&W2[2 * s];           // uniform -> s_load
        h2 wv = pk(wf.x, wf.y);
        h2 a[4] = {u2h(da.x), u2h(da.y), u2h(da.z), u2h(da.w)};
        h2 c[4] = {u2h(dc.x), u2h(dc.y), u2h(dc.z), u2h(dc.w)};
        #pragma unroll
        for (int i2 = 0; i2 < 4; ++i2)
            #pragma unroll
            for (int j2 = 0; j2 < 4; ++j2) {
                h2 p = a[i2] + c[j2];                          // v_pk_add_f16
                p = __builtin_elementwise_max(p, hzero);       // v_pk_max_f16
                acc[i2][j2] = __builtin_amdgcn_fdot2(p, wv, acc[i2][j2], false);
            }
    }

    __syncthreads();                       // all waves done reading rs/ts
    float* red = (float*)smem;             // 8 * 1280 f32 = 40 KB
    {
        float* p = &red[wave * 1280 + lane * 20];
        #pragma unroll
        for (int i2 = 0; i2 < 4; ++i2)
            *(float4*)&p[4 * i2] = make_float4(acc[i2][0], acc[i2][1], acc[i2][2], acc[i2][3]);
    }
    __syncthreads();
    const float b2v = b2[0];
    #pragma unroll
    for (int half = 0; half < 2; ++half) {
        int j = tid + half * 512;          // 0..1023 output elements
        float sum = 0.f;
        #pragma unroll
        for (int w = 0; w < 8; ++w) sum += red[w * 1280 + (j >> 4) * 20 + (j & 15)];
        int ly2 = j >> 7, lx2 = (j >> 4) & 7, dr = (j >> 2) & 3, dt = j & 3;
        out[(rbase + 4 * ly2 + dr) * RT + tbase + 4 * lx2 + dt] = sum + b2v;
    }
}

extern "C" void kernel_launch(void* const* d_in, const int* in_sizes, int n_in,
                              void* d_out, int out_size, void* d_ws, size_t ws_size,
                              hipStream_t stream) {
    const float* robot = (const float*)d_in[0];
    const float* task  = (const float*)d_in[1];
    const float* W1    = (const float*)d_in[2];
    const float* b1    = (const float*)d_in[3];
    const float* W2    = (const float*)d_in[4];
    const float* b2    = (const float*)d_in[5];
    float* out = (float*)d_out;
    unsigned* wsu = (unsigned*)d_ws;   // 1 MB packed rp/tp

    gemm_packed<<<dim3(256), 256, 0, stream>>>(robot, task, W1, b1, wsu);
    score<<<dim3(16, 16), 512, 0, stream>>>(wsu, W2, b2, out);
}